// Round 1
// baseline (365.382 us; speedup 1.0000x reference)
//
#include <hip/hip_runtime.h>
#include <math.h>

#define NS_DIM    8
#define NS_NCOND  16
#define NS_K      5
#define NS_NFLOWS 2
#define NS_HID    8
#define NS_CMAX   23   // NCOND + DIM - 1
#define NS_TB     3.0f
#define NS_MINW   0.001f
#define NS_MIND   0.001f

__device__ __forceinline__ float fast_tanhf(float x) {
    // tanh(x) = 1 - 2/(exp(2x)+1); exact limits at +-inf overflow
    float e = __expf(2.0f * x);
    return 1.0f - 2.0f / (e + 1.0f);
}

__device__ __forceinline__ float softplusf_(float x) {
    // logaddexp(x, 0) = max(x,0) + log1p(exp(-|x|))
    return fmaxf(x, 0.0f) + __logf(1.0f + __expf(-fabsf(x)));
}

// out[k] = scale * softmax(in)[k]
__device__ __forceinline__ void softmax5(const float* in, float* out, float scale) {
    float m = in[0];
#pragma unroll
    for (int k = 1; k < NS_K; ++k) m = fmaxf(m, in[k]);
    float e[NS_K];
    float s = 0.0f;
#pragma unroll
    for (int k = 0; k < NS_K; ++k) { e[k] = __expf(in[k] - m); s += e[k]; }
    float inv = scale / s;
#pragma unroll
    for (int k = 0; k < NS_K; ++k) out[k] = e[k] * inv;
}

__global__ __launch_bounds__(256)
void nsf_kernel(const float* __restrict__ x_inp, const float* __restrict__ cond_inp,
                const float* __restrict__ Wi1, const float* __restrict__ bi1,
                const float* __restrict__ Wi2, const float* __restrict__ bi2,
                const float* __restrict__ Wi3, const float* __restrict__ bi3,
                const float* __restrict__ Wf1, const float* __restrict__ bf1,
                const float* __restrict__ Wf2, const float* __restrict__ bf2,
                const float* __restrict__ Wf3, const float* __restrict__ bf3,
                float* __restrict__ out, int N)
{
    int n = blockIdx.x * blockDim.x + threadIdx.x;
    if (n >= N) return;

    // ---- load per-sample inputs (vectorized, coalesced) ----
    float xv[NS_DIM];
    {
        const float4* xp = (const float4*)(x_inp + (size_t)n * NS_DIM);
        float4 a = xp[0], b = xp[1];
        xv[0]=a.x; xv[1]=a.y; xv[2]=a.z; xv[3]=a.w;
        xv[4]=b.x; xv[5]=b.y; xv[6]=b.z; xv[7]=b.w;
    }
    float cond[NS_CMAX];
    {
        const float4* cp = (const float4*)(cond_inp + (size_t)n * NS_NCOND);
        float4 c0 = cp[0], c1 = cp[1], c2 = cp[2], c3 = cp[3];
        cond[0]=c0.x; cond[1]=c0.y; cond[2]=c0.z;  cond[3]=c0.w;
        cond[4]=c1.x; cond[5]=c1.y; cond[6]=c1.z;  cond[7]=c1.w;
        cond[8]=c2.x; cond[9]=c2.y; cond[10]=c2.z; cond[11]=c2.w;
        cond[12]=c3.x; cond[13]=c3.y; cond[14]=c3.z; cond[15]=c3.w;
    }

    float total = 0.0f;

#pragma unroll 1
    for (int jd = 0; jd < NS_DIM; ++jd) {
        // autoregressive tail of cond_jd: x_inp[:, :jd], zero-padded
#pragma unroll
        for (int t = 0; t < NS_DIM - 1; ++t)
            cond[NS_NCOND + t] = (t < jd) ? xv[t] : 0.0f;

        // ---------- gaussian-base network ----------
        float g0, g1;
        {
            const float* W1 = Wi1 + (size_t)jd * NS_HID * NS_CMAX;
            const float* b1 = bi1 + (size_t)jd * NS_HID;
            const float* W2 = Wi2 + (size_t)jd * NS_HID * NS_HID;
            const float* b2 = bi2 + (size_t)jd * NS_HID;
            const float* W3 = Wi3 + (size_t)jd * 2 * NS_HID;
            const float* b3 = bi3 + (size_t)jd * 2;
            float h1[NS_HID], h2[NS_HID];
#pragma unroll
            for (int i = 0; i < NS_HID; ++i) {
                float acc = b1[i];
#pragma unroll
                for (int c = 0; c < NS_CMAX; ++c)
                    acc = fmaf(W1[i * NS_CMAX + c], cond[c], acc);
                h1[i] = fast_tanhf(acc);
            }
#pragma unroll
            for (int i = 0; i < NS_HID; ++i) {
                float acc = b2[i];
#pragma unroll
                for (int k = 0; k < NS_HID; ++k)
                    acc = fmaf(W2[i * NS_HID + k], h1[k], acc);
                h2[i] = fast_tanhf(acc);
            }
            g0 = b3[0]; g1 = b3[1];
#pragma unroll
            for (int k = 0; k < NS_HID; ++k) {
                g0 = fmaf(W3[k], h2[k], g0);
                g1 = fmaf(W3[NS_HID + k], h2[k], g1);
            }
        }

        // ---------- flows ----------
        float xcur = xv[jd];
        float ldsum = 0.0f;
#pragma unroll 1
        for (int jf = 0; jf < NS_NFLOWS; ++jf) {
            const int nf = jd * NS_NFLOWS + jf;
            const float* F1  = Wf1 + (size_t)nf * NS_HID * NS_CMAX;
            const float* fb1 = bf1 + (size_t)nf * NS_HID;
            const float* F2  = Wf2 + (size_t)nf * NS_HID * NS_HID;
            const float* fb2 = bf2 + (size_t)nf * NS_HID;
            const float* F3  = Wf3 + (size_t)nf * (3 * NS_K - 1) * NS_HID;
            const float* fb3 = bf3 + (size_t)nf * (3 * NS_K - 1);

            float h1[NS_HID], h2[NS_HID];
#pragma unroll
            for (int i = 0; i < NS_HID; ++i) {
                float acc = fb1[i];
#pragma unroll
                for (int c = 0; c < NS_CMAX; ++c)
                    acc = fmaf(F1[i * NS_CMAX + c], cond[c], acc);
                h1[i] = fast_tanhf(acc);
            }
#pragma unroll
            for (int i = 0; i < NS_HID; ++i) {
                float acc = fb2[i];
#pragma unroll
                for (int k = 0; k < NS_HID; ++k)
                    acc = fmaf(F2[i * NS_HID + k], h1[k], acc);
                h2[i] = fast_tanhf(acc);
            }
            float o[3 * NS_K - 1];
#pragma unroll
            for (int i = 0; i < 3 * NS_K - 1; ++i) {
                float acc = fb3[i];
#pragma unroll
                for (int k = 0; k < NS_HID; ++k)
                    acc = fmaf(F3[i * NS_HID + k], h2[k], acc);
                o[i] = acc;
            }

            // ---------- RQS spline ----------
            // reference applies softmax TWICE to widths/heights:
            // W = 2*TB*softmax(o[:5]); widths = MINW + (1-5*MINW)*softmax(W)
            float t5[NS_K], u5[NS_K];
            softmax5(&o[0], u5, 2.0f * NS_TB);
            softmax5(u5, t5, 1.0f - NS_MINW * NS_K);
            float cw[NS_K + 1], bw[NS_K];
            {
                float run = 0.0f;
                cw[0] = -NS_TB;
#pragma unroll
                for (int k = 0; k < NS_K; ++k) {
                    run += NS_MINW + t5[k];
                    cw[k + 1] = 2.0f * NS_TB * run - NS_TB;
                }
                cw[NS_K] = NS_TB;
#pragma unroll
                for (int k = 0; k < NS_K; ++k) bw[k] = cw[k + 1] - cw[k];
            }
            softmax5(&o[NS_K], u5, 2.0f * NS_TB);
            softmax5(u5, t5, 1.0f - NS_MINW * NS_K);
            float ch[NS_K + 1], bh[NS_K];
            {
                float run = 0.0f;
                ch[0] = -NS_TB;
#pragma unroll
                for (int k = 0; k < NS_K; ++k) {
                    run += NS_MINW + t5[k];
                    ch[k + 1] = 2.0f * NS_TB * run - NS_TB;
                }
                ch[NS_K] = NS_TB;
#pragma unroll
                for (int k = 0; k < NS_K; ++k) bh[k] = ch[k + 1] - ch[k];
            }
            // derivatives: double softplus on interior, exactly 1.0 at edges
            float dv[NS_K + 1];
            dv[0] = 1.0f; dv[NS_K] = 1.0f;
#pragma unroll
            for (int k = 0; k < NS_K - 1; ++k)
                dv[k + 1] = NS_MIND + softplusf_(softplusf_(o[2 * NS_K + k]));

            float xc = fminf(fmaxf(xcur, -NS_TB), NS_TB);
            int idx = (xc >= cw[1]) + (xc >= cw[2]) + (xc >= cw[3]) + (xc >= cw[4]);

            float icw = cw[0], ibw = bw[0], ich = ch[0], ih = bh[0], d0 = dv[0], d1 = dv[1];
#pragma unroll
            for (int k = 1; k < NS_K; ++k) {
                bool sel = (idx == k);
                icw = sel ? cw[k] : icw;
                ibw = sel ? bw[k] : ibw;
                ich = sel ? ch[k] : ich;
                ih  = sel ? bh[k] : ih;
                d0  = sel ? dv[k] : d0;
                d1  = sel ? dv[k + 1] : d1;
            }

            float idelta = ih / ibw;
            float th   = (xc - icw) / ibw;
            float t2   = th * th;
            float omt  = 1.0f - th;
            float tomt = th * omt;
            float den  = idelta + (d0 + d1 - 2.0f * idelta) * tomt;
            float zin  = ich + ih * (idelta * t2 + d0 * tomt) / den;
            float num  = idelta * idelta * (d1 * t2 + 2.0f * idelta * tomt + d0 * omt * omt);
            float ldin = __logf(num) - 2.0f * __logf(den);

            bool inside = (xcur >= -NS_TB) && (xcur <= NS_TB);
            xcur  = inside ? zin : xcur;
            ldsum = inside ? (ldsum + ldin) : ldsum;
        }

        // ---------- gaussian base log-prob ----------
        float sig = __expf(g1);
        float z = (xcur - g0) / sig;
        float lp = -(z + __expf(-z)) - __logf(sig);
        if (isnan(lp) || isinf(lp)) lp = -100.0f;
        total += ldsum + lp;
    }

    out[n] = total;
}

extern "C" void kernel_launch(void* const* d_in, const int* in_sizes, int n_in,
                              void* d_out, int out_size, void* d_ws, size_t ws_size,
                              hipStream_t stream) {
    const float* x_inp    = (const float*)d_in[0];
    const float* cond_inp = (const float*)d_in[1];
    const float* Wi1 = (const float*)d_in[2];
    const float* bi1 = (const float*)d_in[3];
    const float* Wi2 = (const float*)d_in[4];
    const float* bi2 = (const float*)d_in[5];
    const float* Wi3 = (const float*)d_in[6];
    const float* bi3 = (const float*)d_in[7];
    const float* Wf1 = (const float*)d_in[8];
    const float* bf1 = (const float*)d_in[9];
    const float* Wf2 = (const float*)d_in[10];
    const float* bf2 = (const float*)d_in[11];
    const float* Wf3 = (const float*)d_in[12];
    const float* bf3 = (const float*)d_in[13];
    float* out = (float*)d_out;

    int N = out_size;
    int block = 256;
    int grid = (N + block - 1) / block;
    hipLaunchKernelGGL(nsf_kernel, dim3(grid), dim3(block), 0, stream,
                       x_inp, cond_inp, Wi1, bi1, Wi2, bi2, Wi3, bi3,
                       Wf1, bf1, Wf2, bf2, Wf3, bf3, out, N);
}

// Round 2
// 350.778 us; speedup vs baseline: 1.0416x; 1.0416x over previous
//
#include <hip/hip_runtime.h>
#include <math.h>

__device__ __forceinline__ float rcp_(float x) { return __fdividef(1.0f, x); }

__device__ __forceinline__ float tanh_(float x) {
    float e = __expf(x + x);                 // exp(2x); inf/0 at extremes -> exact +-1
    return fmaf(-2.0f, rcp_(e + 1.0f), 1.0f);
}

__device__ __forceinline__ float sp_(float x) {
    // softplus: max(x,0) + log1p(exp(-|x|))
    return fmaxf(x, 0.0f) + __logf(1.0f + __expf(-fabsf(x)));
}

// w[k] = 0.001 + 0.995 * softmax( 6 * softmax(o) )[k]
// trick: max of u = 6*softmax(o) is exactly 6*rcp(s) since max exp term == 1.0
__device__ __forceinline__ void dsm5_(float o0, float o1, float o2, float o3, float o4,
                                      float* __restrict__ w) {
    float m  = fmaxf(fmaxf(fmaxf(o0, o1), fmaxf(o2, o3)), o4);
    float e0 = __expf(o0 - m), e1 = __expf(o1 - m), e2 = __expf(o2 - m),
          e3 = __expf(o3 - m), e4 = __expf(o4 - m);
    float inv = 6.0f * rcp_(((e0 + e1) + (e2 + e3)) + e4);   // == max(u)
    float f0 = __expf(fmaf(e0, inv, -inv));
    float f1 = __expf(fmaf(e1, inv, -inv));
    float f2 = __expf(fmaf(e2, inv, -inv));
    float f3 = __expf(fmaf(e3, inv, -inv));
    float f4 = __expf(fmaf(e4, inv, -inv));
    float t  = 0.995f * rcp_(((f0 + f1) + (f2 + f3)) + f4);
    w[0] = fmaf(f0, t, 0.001f);
    w[1] = fmaf(f1, t, 0.001f);
    w[2] = fmaf(f2, t, 0.001f);
    w[3] = fmaf(f3, t, 0.001f);
    w[4] = fmaf(f4, t, 0.001f);
}

// 23 -> 8 tanh -> 8 tanh
__device__ __forceinline__ void mlp2_(const float* __restrict__ W1, const float* __restrict__ b1,
                                      const float* __restrict__ W2, const float* __restrict__ b2,
                                      const float* __restrict__ cond, float* __restrict__ h2) {
    float h1[8];
#pragma unroll
    for (int i = 0; i < 8; ++i) {
        float a = b1[i];
#pragma unroll
        for (int c = 0; c < 23; ++c) a = fmaf(W1[i * 23 + c], cond[c], a);
        h1[i] = tanh_(a);
    }
#pragma unroll
    for (int i = 0; i < 8; ++i) {
        float a = b2[i];
#pragma unroll
        for (int c = 0; c < 8; ++c) a = fmaf(W2[i * 8 + c], h1[c], a);
        h2[i] = tanh_(a);
    }
}

__global__ __launch_bounds__(256)
void nsf_kernel(const float* __restrict__ x_inp, const float* __restrict__ cond_inp,
                const float* __restrict__ Wi1, const float* __restrict__ bi1,
                const float* __restrict__ Wi2, const float* __restrict__ bi2,
                const float* __restrict__ Wi3, const float* __restrict__ bi3,
                const float* __restrict__ Wf1, const float* __restrict__ bf1,
                const float* __restrict__ Wf2, const float* __restrict__ bf2,
                const float* __restrict__ Wf3, const float* __restrict__ bf3,
                float* __restrict__ out, int N)
{
    int n = blockIdx.x * blockDim.x + threadIdx.x;
    if (n >= N) return;

    float xv[8];
    {
        const float4* xp = (const float4*)(x_inp + (size_t)n * 8);
        float4 a = xp[0], b = xp[1];
        xv[0]=a.x; xv[1]=a.y; xv[2]=a.z; xv[3]=a.w;
        xv[4]=b.x; xv[5]=b.y; xv[6]=b.z; xv[7]=b.w;
    }
    float cond[23];
    {
        const float4* cp = (const float4*)(cond_inp + (size_t)n * 16);
        float4 c0 = cp[0], c1 = cp[1], c2 = cp[2], c3 = cp[3];
        cond[0]=c0.x;  cond[1]=c0.y;  cond[2]=c0.z;  cond[3]=c0.w;
        cond[4]=c1.x;  cond[5]=c1.y;  cond[6]=c1.z;  cond[7]=c1.w;
        cond[8]=c2.x;  cond[9]=c2.y;  cond[10]=c2.z; cond[11]=c2.w;
        cond[12]=c3.x; cond[13]=c3.y; cond[14]=c3.z; cond[15]=c3.w;
    }

    float total = 0.0f;

#pragma unroll 1
    for (int jd = 0; jd < 8; ++jd) {
        // autoregressive tail (static indices only -> stays in registers)
#pragma unroll
        for (int t = 0; t < 7; ++t)
            cond[16 + t] = (t < jd) ? xv[t] : 0.0f;

        // ---------- gaussian-base network ----------
        float g0, g1;
        {
            float h2[8];
            mlp2_(Wi1 + jd * 184, bi1 + jd * 8, Wi2 + jd * 64, bi2 + jd * 8, cond, h2);
            const float* W3 = Wi3 + jd * 16;
            const float* b3 = bi3 + jd * 2;
            g0 = b3[0]; g1 = b3[1];
#pragma unroll
            for (int c = 0; c < 8; ++c) {
                g0 = fmaf(W3[c], h2[c], g0);
                g1 = fmaf(W3[8 + c], h2[c], g1);
            }
        }

        // ---------- flows ----------
        float xcur = xv[jd];
        float ldsum = 0.0f;
#pragma unroll 1
        for (int jf = 0; jf < 2; ++jf) {
            const int nf = jd * 2 + jf;
            float h2[8];
            mlp2_(Wf1 + (size_t)nf * 184, bf1 + nf * 8,
                  Wf2 + (size_t)nf * 64,  bf2 + nf * 8, cond, h2);
            float o[14];
            {
                const float* F3  = Wf3 + (size_t)nf * 112;
                const float* fb3 = bf3 + nf * 14;
#pragma unroll
                for (int i = 0; i < 14; ++i) {
                    float a = fb3[i];
#pragma unroll
                    for (int c = 0; c < 8; ++c) a = fmaf(F3[i * 8 + c], h2[c], a);
                    o[i] = a;
                }
            }

            // ---------- RQS spline ----------
            float wv[5], hv[5];
            dsm5_(o[0], o[1], o[2], o[3], o[4], wv);
            dsm5_(o[5], o[6], o[7], o[8], o[9], hv);
            float di1 = 0.001f + sp_(sp_(o[10]));
            float di2 = 0.001f + sp_(sp_(o[11]));
            float di3 = 0.001f + sp_(sp_(o[12]));
            float di4 = 0.001f + sp_(sp_(o[13]));

            float xc = fminf(fmaxf(xcur, -3.0f), 3.0f);

            // incremental edge computation + bin selection (no arrays)
            float runw = wv[0], runh = hv[0];
            float cwL = -3.0f, chL = -3.0f;
            float cwR = fmaf(6.0f, runw, -3.0f);
            float chR = fmaf(6.0f, runh, -3.0f);
            float icw = cwL, ibw = cwR - cwL, ich = chL, ihh = chR - chL;
            float d0 = 1.0f, d1 = di1;
#pragma unroll
            for (int k = 1; k < 5; ++k) {
                cwL = cwR; chL = chR;
                runw += wv[k]; runh += hv[k];
                cwR = (k == 4) ? 3.0f : fmaf(6.0f, runw, -3.0f);
                chR = (k == 4) ? 3.0f : fmaf(6.0f, runh, -3.0f);
                float dk0 = (k == 1) ? di1 : (k == 2) ? di2 : (k == 3) ? di3 : di4;
                float dk1 = (k == 1) ? di2 : (k == 2) ? di3 : (k == 3) ? di4 : 1.0f;
                bool sel = (xc >= cwL);
                icw = sel ? cwL : icw;
                ibw = sel ? (cwR - cwL) : ibw;
                ich = sel ? chL : ich;
                ihh = sel ? (chR - chL) : ihh;
                d0  = sel ? dk0 : d0;
                d1  = sel ? dk1 : d1;
            }

            float rb     = rcp_(ibw);          // shared: idelta and th
            float idelta = ihh * rb;
            float th     = (xc - icw) * rb;
            float t2     = th * th;
            float omt    = 1.0f - th;
            float tomt   = th * omt;
            float den    = fmaf(fmaf(-2.0f, idelta, d0 + d1), tomt, idelta);
            float rden   = rcp_(den);
            float xn     = fmaf(ihh * fmaf(idelta, t2, d0 * tomt), rden, ich);
            float num    = (idelta * idelta) *
                           fmaf(d1, t2, fmaf(idelta + idelta, tomt, d0 * (omt * omt)));
            float ldi    = __logf((num * rden) * rden);   // log(num) - 2 log(den)

            bool inside = (xcur >= -3.0f) && (xcur <= 3.0f);
            xcur  = inside ? xn : xcur;
            ldsum = inside ? (ldsum + ldi) : ldsum;
        }

        // ---------- gaussian base log-prob: log(sig) == g1, 1/sig == exp(-g1) ----------
        float z  = (xcur - g0) * __expf(-g1);
        float ez = __expf(-z);
        float lp = -(z + ez) - g1;
        if (isnan(lp) || isinf(lp)) lp = -100.0f;
        total += ldsum + lp;
    }

    out[n] = total;
}

extern "C" void kernel_launch(void* const* d_in, const int* in_sizes, int n_in,
                              void* d_out, int out_size, void* d_ws, size_t ws_size,
                              hipStream_t stream) {
    const float* x_inp    = (const float*)d_in[0];
    const float* cond_inp = (const float*)d_in[1];
    const float* Wi1 = (const float*)d_in[2];
    const float* bi1 = (const float*)d_in[3];
    const float* Wi2 = (const float*)d_in[4];
    const float* bi2 = (const float*)d_in[5];
    const float* Wi3 = (const float*)d_in[6];
    const float* bi3 = (const float*)d_in[7];
    const float* Wf1 = (const float*)d_in[8];
    const float* bf1 = (const float*)d_in[9];
    const float* Wf2 = (const float*)d_in[10];
    const float* bf2 = (const float*)d_in[11];
    const float* Wf3 = (const float*)d_in[12];
    const float* bf3 = (const float*)d_in[13];
    float* out = (float*)d_out;

    int N = out_size;
    int block = 256;
    int grid = (N + block - 1) / block;
    hipLaunchKernelGGL(nsf_kernel, dim3(grid), dim3(block), 0, stream,
                       x_inp, cond_inp, Wi1, bi1, Wi2, bi2, Wi3, bi3,
                       Wf1, bf1, Wf2, bf2, Wf3, bf3, out, N);
}

// Round 3
// 306.849 us; speedup vs baseline: 1.1908x; 1.1432x over previous
//
#include <hip/hip_runtime.h>
#include <math.h>

typedef float v2 __attribute__((ext_vector_type(2)));

__device__ __forceinline__ float rcp1_(float x) { return __fdividef(1.0f, x); }
__device__ __forceinline__ v2 v2s(float s) { return (v2){s, s}; }
__device__ __forceinline__ v2 expv(v2 x) { return (v2){__expf(x.x), __expf(x.y)}; }
__device__ __forceinline__ v2 logv(v2 x) { return (v2){__logf(x.x), __logf(x.y)}; }
__device__ __forceinline__ v2 rcpv(v2 x) { return (v2){rcp1_(x.x), rcp1_(x.y)}; }
__device__ __forceinline__ v2 maxv(v2 a, v2 b) { return __builtin_elementwise_max(a, b); }
__device__ __forceinline__ v2 minv(v2 a, v2 b) { return __builtin_elementwise_min(a, b); }
__device__ __forceinline__ v2 absv(v2 a) { return (v2){__builtin_fabsf(a.x), __builtin_fabsf(a.y)}; }

// componentwise select: (x >= e) ? a : b
__device__ __forceinline__ v2 selge(v2 x, v2 e, v2 a, v2 b) {
    v2 r;
    r.x = (x.x >= e.x) ? a.x : b.x;
    r.y = (x.y >= e.y) ? a.y : b.y;
    return r;
}

__device__ __forceinline__ v2 tanhv(v2 x) {
    v2 e = expv(x + x);
    return v2s(1.0f) - v2s(2.0f) * rcpv(e + v2s(1.0f));
}

__device__ __forceinline__ v2 spv(v2 x) {   // softplus
    return maxv(x, v2s(0.0f)) + logv(v2s(1.0f) + expv(-absv(x)));
}

// w[k] = 0.001 + 0.995 * softmax(6 * softmax(o))[k]; max of inner-scaled vec is 6/s
__device__ __forceinline__ void dsm5v(v2 o0, v2 o1, v2 o2, v2 o3, v2 o4, v2* __restrict__ w) {
    v2 m = maxv(maxv(maxv(o0, o1), maxv(o2, o3)), o4);
    v2 e0 = expv(o0 - m), e1 = expv(o1 - m), e2 = expv(o2 - m),
       e3 = expv(o3 - m), e4 = expv(o4 - m);
    v2 inv = v2s(6.0f) * rcpv(((e0 + e1) + (e2 + e3)) + e4);
    v2 f0 = expv(e0 * inv - inv);
    v2 f1 = expv(e1 * inv - inv);
    v2 f2 = expv(e2 * inv - inv);
    v2 f3 = expv(e3 * inv - inv);
    v2 f4 = expv(e4 * inv - inv);
    v2 t = v2s(0.995f) * rcpv(((f0 + f1) + (f2 + f3)) + f4);
    w[0] = f0 * t + v2s(0.001f);
    w[1] = f1 * t + v2s(0.001f);
    w[2] = f2 * t + v2s(0.001f);
    w[3] = f3 * t + v2s(0.001f);
    w[4] = f4 * t + v2s(0.001f);
}

// 23 -> 8 tanh -> 8 tanh, weights wave-uniform (scalar), activations packed 2-sample
__device__ __forceinline__ void mlp2v(const float* __restrict__ W1, const float* __restrict__ b1,
                                      const float* __restrict__ W2, const float* __restrict__ b2,
                                      const v2* __restrict__ cond, v2* __restrict__ h2) {
    v2 h1[8];
#pragma unroll
    for (int i = 0; i < 8; ++i) {
        v2 a = v2s(b1[i]);
#pragma unroll
        for (int c = 0; c < 23; ++c) a = v2s(W1[i * 23 + c]) * cond[c] + a;
        h1[i] = tanhv(a);
    }
#pragma unroll
    for (int i = 0; i < 8; ++i) {
        v2 a = v2s(b2[i]);
#pragma unroll
        for (int c = 0; c < 8; ++c) a = v2s(W2[i * 8 + c]) * h1[c] + a;
        h2[i] = tanhv(a);
    }
}

__global__ __launch_bounds__(256)
void nsf_kernel(const float* __restrict__ x_inp, const float* __restrict__ cond_inp,
                const float* __restrict__ Wi1, const float* __restrict__ bi1,
                const float* __restrict__ Wi2, const float* __restrict__ bi2,
                const float* __restrict__ Wi3, const float* __restrict__ bi3,
                const float* __restrict__ Wf1, const float* __restrict__ bf1,
                const float* __restrict__ Wf2, const float* __restrict__ bf2,
                const float* __restrict__ Wf3, const float* __restrict__ bf3,
                float* __restrict__ out, int N)
{
    int t = blockIdx.x * blockDim.x + threadIdx.x;
    int s0 = 2 * t;
    if (s0 >= N) return;
    bool has2 = (s0 + 1 < N);
    size_t r1 = has2 ? (size_t)(s0 + 1) : (size_t)s0;

    v2 xv[8];
    {
        const float4* a = (const float4*)(x_inp + (size_t)s0 * 8);
        const float4* b = (const float4*)(x_inp + r1 * 8);
        float4 a0 = a[0], a1 = a[1], b0 = b[0], b1 = b[1];
        xv[0] = (v2){a0.x, b0.x}; xv[1] = (v2){a0.y, b0.y};
        xv[2] = (v2){a0.z, b0.z}; xv[3] = (v2){a0.w, b0.w};
        xv[4] = (v2){a1.x, b1.x}; xv[5] = (v2){a1.y, b1.y};
        xv[6] = (v2){a1.z, b1.z}; xv[7] = (v2){a1.w, b1.w};
    }
    v2 cond[23];
    {
        const float4* a = (const float4*)(cond_inp + (size_t)s0 * 16);
        const float4* b = (const float4*)(cond_inp + r1 * 16);
#pragma unroll
        for (int q = 0; q < 4; ++q) {
            float4 ca = a[q], cb = b[q];
            cond[4 * q + 0] = (v2){ca.x, cb.x};
            cond[4 * q + 1] = (v2){ca.y, cb.y};
            cond[4 * q + 2] = (v2){ca.z, cb.z};
            cond[4 * q + 3] = (v2){ca.w, cb.w};
        }
    }

    v2 total = v2s(0.0f);

#pragma unroll 1
    for (int jd = 0; jd < 8; ++jd) {
#pragma unroll
        for (int q = 0; q < 7; ++q)
            cond[16 + q] = (q < jd) ? xv[q] : v2s(0.0f);

        // ---------- gaussian-base network ----------
        v2 g0, g1;
        {
            v2 h2[8];
            mlp2v(Wi1 + jd * 184, bi1 + jd * 8, Wi2 + jd * 64, bi2 + jd * 8, cond, h2);
            const float* W3 = Wi3 + jd * 16;
            const float* b3 = bi3 + jd * 2;
            g0 = v2s(b3[0]); g1 = v2s(b3[1]);
#pragma unroll
            for (int c = 0; c < 8; ++c) {
                g0 = v2s(W3[c]) * h2[c] + g0;
                g1 = v2s(W3[8 + c]) * h2[c] + g1;
            }
        }

        // ---------- flows ----------
        v2 xcur = xv[jd];
        v2 ldsum = v2s(0.0f);
#pragma unroll 1
        for (int jf = 0; jf < 2; ++jf) {
            const int nf = jd * 2 + jf;
            v2 h2[8];
            mlp2v(Wf1 + (size_t)nf * 184, bf1 + nf * 8,
                  Wf2 + (size_t)nf * 64,  bf2 + nf * 8, cond, h2);
            v2 o[14];
            {
                const float* F3  = Wf3 + (size_t)nf * 112;
                const float* fb3 = bf3 + nf * 14;
#pragma unroll
                for (int i = 0; i < 14; ++i) {
                    v2 a = v2s(fb3[i]);
#pragma unroll
                    for (int c = 0; c < 8; ++c) a = v2s(F3[i * 8 + c]) * h2[c] + a;
                    o[i] = a;
                }
            }

            // ---------- RQS spline ----------
            v2 wv[5], hv[5];
            dsm5v(o[0], o[1], o[2], o[3], o[4], wv);
            dsm5v(o[5], o[6], o[7], o[8], o[9], hv);
            v2 di1 = spv(spv(o[10])) + v2s(0.001f);
            v2 di2 = spv(spv(o[11])) + v2s(0.001f);
            v2 di3 = spv(spv(o[12])) + v2s(0.001f);
            v2 di4 = spv(spv(o[13])) + v2s(0.001f);

            v2 xc = minv(maxv(xcur, v2s(-3.0f)), v2s(3.0f));

            v2 runw = wv[0], runh = hv[0];
            v2 cwL = v2s(-3.0f), chL = v2s(-3.0f);
            v2 cwR = v2s(6.0f) * runw + v2s(-3.0f);
            v2 chR = v2s(6.0f) * runh + v2s(-3.0f);
            v2 icw = cwL, ibw = cwR - cwL, ich = chL, ihh = chR - chL;
            v2 d0 = v2s(1.0f), d1 = di1;
#pragma unroll
            for (int k = 1; k < 5; ++k) {
                cwL = cwR; chL = chR;
                runw += wv[k]; runh += hv[k];
                cwR = (k == 4) ? v2s(3.0f) : v2s(6.0f) * runw + v2s(-3.0f);
                chR = (k == 4) ? v2s(3.0f) : v2s(6.0f) * runh + v2s(-3.0f);
                v2 dk0 = (k == 1) ? di1 : (k == 2) ? di2 : (k == 3) ? di3 : di4;
                v2 dk1 = (k == 1) ? di2 : (k == 2) ? di3 : (k == 3) ? di4 : v2s(1.0f);
                icw = selge(xc, cwL, cwL, icw);
                ibw = selge(xc, cwL, cwR - cwL, ibw);
                ich = selge(xc, cwL, chL, ich);
                ihh = selge(xc, cwL, chR - chL, ihh);
                d0  = selge(xc, cwL, dk0, d0);
                d1  = selge(xc, cwL, dk1, d1);
            }

            v2 rb     = rcpv(ibw);
            v2 idelta = ihh * rb;
            v2 th     = (xc - icw) * rb;
            v2 t2     = th * th;
            v2 omt    = v2s(1.0f) - th;
            v2 tomt   = th * omt;
            v2 den    = (d0 + d1 - v2s(2.0f) * idelta) * tomt + idelta;
            v2 rden   = rcpv(den);
            v2 xn     = ihh * (idelta * t2 + d0 * tomt) * rden + ich;
            v2 num    = (idelta * idelta) *
                        (d1 * t2 + (idelta + idelta) * tomt + d0 * (omt * omt));
            v2 ldi    = logv((num * rden) * rden);

            // inside = -3 <= xcur <= 3 (componentwise)
            v2 nxt, nld;
            nxt.x = (xcur.x >= -3.0f && xcur.x <= 3.0f) ? xn.x : xcur.x;
            nxt.y = (xcur.y >= -3.0f && xcur.y <= 3.0f) ? xn.y : xcur.y;
            nld.x = (xcur.x >= -3.0f && xcur.x <= 3.0f) ? (ldsum.x + ldi.x) : ldsum.x;
            nld.y = (xcur.y >= -3.0f && xcur.y <= 3.0f) ? (ldsum.y + ldi.y) : ldsum.y;
            xcur = nxt; ldsum = nld;
        }

        // ---------- gaussian base log-prob ----------
        v2 z  = (xcur - g0) * expv(-g1);
        v2 ez = expv(-z);
        v2 lp = -(z + ez) - g1;
        lp.x = (isnan(lp.x) || isinf(lp.x)) ? -100.0f : lp.x;
        lp.y = (isnan(lp.y) || isinf(lp.y)) ? -100.0f : lp.y;
        total += ldsum + lp;
    }

    if (has2) {
        float2 st; st.x = total.x; st.y = total.y;
        *(float2*)(out + (size_t)s0) = st;
    } else {
        out[s0] = total.x;
    }
}

extern "C" void kernel_launch(void* const* d_in, const int* in_sizes, int n_in,
                              void* d_out, int out_size, void* d_ws, size_t ws_size,
                              hipStream_t stream) {
    const float* x_inp    = (const float*)d_in[0];
    const float* cond_inp = (const float*)d_in[1];
    const float* Wi1 = (const float*)d_in[2];
    const float* bi1 = (const float*)d_in[3];
    const float* Wi2 = (const float*)d_in[4];
    const float* bi2 = (const float*)d_in[5];
    const float* Wi3 = (const float*)d_in[6];
    const float* bi3 = (const float*)d_in[7];
    const float* Wf1 = (const float*)d_in[8];
    const float* bf1 = (const float*)d_in[9];
    const float* Wf2 = (const float*)d_in[10];
    const float* bf2 = (const float*)d_in[11];
    const float* Wf3 = (const float*)d_in[12];
    const float* bf3 = (const float*)d_in[13];
    float* out = (float*)d_out;

    int N = out_size;
    int nthreads = (N + 1) / 2;
    int block = 256;
    int grid = (nthreads + block - 1) / block;
    hipLaunchKernelGGL(nsf_kernel, dim3(grid), dim3(block), 0, stream,
                       x_inp, cond_inp, Wi1, bi1, Wi2, bi2, Wi3, bi3,
                       Wf1, bf1, Wf2, bf2, Wf3, bf3, out, N);
}